// Round 5
// baseline (2439.726 us; speedup 1.0000x reference)
//
#include <hip/hip_runtime.h>
#include <cstdint>
#include <cstddef>

#define BATCH   4
#define NPTS    16384
#define NPOINT  1024
#define NSAMPLE 32
#define CIN     67          // 3 + 64 feature channels
#define R2f     0.04f       // (float)(0.2*0.2)

#define FPS_T   1024        // threads per FPS block (16 waves)
#define FPS_PRS 8           // point-PAIRS per thread (16 points)

typedef float v2f __attribute__((ext_vector_type(2)));

#define RPT8(M) M(0)M(1)M(2)M(3)M(4)M(5)M(6)M(7)

// ---------------------------------------------------------------------------
// DPP-based argmax combine: max value, tie -> lowest index. VALU-pipe only.
// ---------------------------------------------------------------------------
template <int CTRL, int RMASK>
__device__ __forceinline__ void amax_dpp(float& v, int& i) {
  int nv = __builtin_amdgcn_update_dpp(__float_as_int(v), __float_as_int(v),
                                       CTRL, RMASK, 0xf, false);
  int ni = __builtin_amdgcn_update_dpp(i, i, CTRL, RMASK, 0xf, false);
  float fv = __int_as_float(nv);
  bool tk = (fv > v) || (fv == v && ni < i);
  v = tk ? fv : v;
  i = tk ? ni : i;
}

// ---------------------------------------------------------------------------
// FPS: one block (1024 threads = 16 waves) per batch, 16 points/thread.
// State = 64 floats/thread (xy as float2, z packed in cross-point pairs,
// dist scalars) -> fits the 128-reg tier at launch_bounds(1024,4) WITHOUT
// the AGPR split that plagued the 128-float/thread versions (R1-R4: state
// silently lived in AGPRs, ~2x VALU inflation from accvgpr moves; WRITE_SIZE
// 48KB + FETCH 408KB proved no scratch/global traffic).
// Distance math uses float2 ops -> v_pk_sub/mul_f32 (per-half RN, bit-exact
// vs scalar; sum order (dx^2+dy^2)+dz^2 matches the np reference exactly, so
// the argmax sequence is preserved).
// ---------------------------------------------------------------------------
__global__ __launch_bounds__(FPS_T, 4) void fps_kernel(
    const float* __restrict__ xyz, float* __restrict__ out_newxyz)
{
  const int b = blockIdx.x;
  const float* base = xyz + (size_t)b * NPTS * 3;
  const int t = threadIdx.x;
  const int lane = t & 63, w = t >> 6;

  // pair p covers points j0=2p, j1=2p+1 (global idx = (j<<10)+t)
#define DECLP(p) v2f xa##p, xb##p, zz##p; float da##p, db##p;
  RPT8(DECLP)
#undef DECLP
#define LOADP(p) { const float* q0 = base + (size_t)(((2*(p)) << 10) + t) * 3; \
                   const float* q1 = base + (size_t)(((2*(p)+1) << 10) + t) * 3; \
                   xa##p.x = q0[0]; xa##p.y = q0[1]; \
                   xb##p.x = q1[0]; xb##p.y = q1[1]; \
                   zz##p.x = q0[2]; zz##p.y = q1[2]; \
                   da##p = 1e10f;  db##p = 1e10f; }
  RPT8(LOADP)
#undef LOADP

  __shared__ float s_wv[2][16];
  __shared__ int   s_wi[2][16];

  v2f cxy; cxy.x = base[0]; cxy.y = base[1];
  v2f czz; czz.x = base[2]; czz.y = base[2];

  for (int it = 0; it < NPOINT; ++it) {
    if (t == 0) {                       // record centroid (pre-update far)
      int o = (b * NPOINT + it) * 3;
      out_newxyz[o + 0] = cxy.x;
      out_newxyz[o + 1] = cxy.y;
      out_newxyz[o + 2] = czz.x;
    }
    float bv = -1.0f; int bl = 0;
    // ascending j order preserves "lowest index wins" tie-break vs np.argmax
#define STEPP(p) { \
    v2f d0 = xa##p - cxy;  v2f d1 = xb##p - cxy;  v2f dz = zz##p - czz; \
    v2f q0 = d0 * d0;      v2f q1 = d1 * d1;      v2f qz = dz * dz; \
    float s0 = __fadd_rn(__fadd_rn(q0.x, q0.y), qz.x); \
    float s1 = __fadd_rn(__fadd_rn(q1.x, q1.y), qz.y); \
    float n0 = fminf(da##p, s0); da##p = n0; \
    float n1 = fminf(db##p, s1); db##p = n1; \
    bool t0 = n0 > bv; bv = t0 ? n0 : bv; bl = t0 ? (2*(p)) : bl; \
    bool t1 = n1 > bv; bv = t1 ? n1 : bv; bl = t1 ? (2*(p)+1) : bl; }
    RPT8(STEPP)
#undef STEPP
    int bi = (bl << 10) + t;            // global point index

    // wave argmax via DPP (VALU pipe); result valid in lane 63
    amax_dpp<0x121, 0xf>(bv, bi);       // row_ror:1
    amax_dpp<0x122, 0xf>(bv, bi);       // row_ror:2
    amax_dpp<0x124, 0xf>(bv, bi);       // row_ror:4
    amax_dpp<0x128, 0xf>(bv, bi);       // row_ror:8  -> row maxima
    amax_dpp<0x142, 0xa>(bv, bi);       // row_bcast15 -> rows 1,3
    amax_dpp<0x143, 0xc>(bv, bi);       // row_bcast31 -> lane63 has full wave

    const int par = it & 1;
    if (lane == 63) { s_wv[par][w] = bv; s_wi[par][w] = bi; }
    __syncthreads();

    float gv = s_wv[par][lane & 15];    // period-16 broadcast: no conflicts
    int   gi = s_wi[par][lane & 15];
    amax_dpp<0x121, 0xf>(gv, gi);       // 4 ror levels reduce the 16 entries
    amax_dpp<0x122, 0xf>(gv, gi);
    amax_dpp<0x124, 0xf>(gv, gi);
    amax_dpp<0x128, 0xf>(gv, gi);

    int far = __builtin_amdgcn_readfirstlane(gi);
    cxy.x = base[far * 3 + 0];          // uniform centroid load
    cxy.y = base[far * 3 + 1];
    czz.x = base[far * 3 + 2];
    czz.y = czz.x;
  }
}

// ---------------------------------------------------------------------------
// features (B,64,N) -> featsT (B,N,64) so per-neighbor gathers are contiguous.
// ---------------------------------------------------------------------------
__global__ __launch_bounds__(256) void transpose_kernel(
    const float* __restrict__ f, float* __restrict__ ft)
{
  __shared__ float tile[64][65];
  int b  = blockIdx.x >> 8;
  int n0 = (blockIdx.x & 255) << 6;
  for (int v = threadIdx.x; v < 64 * 64; v += 256) {
    int c = v >> 6, j = v & 63;
    tile[c][j] = f[((size_t)(b * 64 + c)) * NPTS + n0 + j];
  }
  __syncthreads();
  for (int v = threadIdx.x; v < 64 * 64; v += 256) {
    int j = v >> 6, c = v & 63;
    ft[((size_t)(b * NPTS + n0 + j)) * 64 + c] = tile[c][j];
  }
}

// ---------------------------------------------------------------------------
// Fused ball-query + gather + 3-layer MLP + max-pool. (unchanged this round)
// Block = 1024 threads, 8 centers/block, grid = 512.
// ---------------------------------------------------------------------------
__global__ __launch_bounds__(1024) void mlp_kernel(
    const float* __restrict__ xyz,
    const float* __restrict__ feats,      // (B,64,N)
    const float* __restrict__ featsT,     // (B,N,64) or null
    const float* __restrict__ nx,         // new_xyz = d_out base (B,1024,3)
    const float* __restrict__ W1, const float* __restrict__ s1, const float* __restrict__ b1,
    const float* __restrict__ W2, const float* __restrict__ s2, const float* __restrict__ b2,
    const float* __restrict__ W3, const float* __restrict__ s3, const float* __restrict__ b3,
    float* __restrict__ outF)             // d_out + 12288, (B,128,1024)
{
  __shared__ float W1t[CIN * 64];     // [i][o]
  __shared__ float W2t[64 * 64];      // [i][o]
  __shared__ float sb[512];           // s1 b1 s2 b2 s3 b3
  __shared__ float xs[CIN * 34];      // [c][k], pad 34 (2-way = free)
  __shared__ float h1[64 * 34];
  __shared__ float h2[64 * 34];
  __shared__ int   hm[128];
  __shared__ int   lid8[8][NSAMPLE];

  const int tid = threadIdx.x;
  const int lane = tid & 63, w = tid >> 6;

  for (int v = tid; v < CIN * 64; v += 1024) {
    int o = v / CIN, i = v - o * CIN;
    W1t[i * 64 + o] = W1[v];
  }
  for (int v = tid; v < 64 * 64; v += 1024) {
    int o = v >> 6, i = v & 63;
    W2t[i * 64 + o] = W2[v];
  }
  if (tid < 64)       sb[tid]       = s1[tid];
  else if (tid < 128) sb[tid]       = b1[tid - 64];
  else if (tid < 192) sb[tid]       = s2[tid - 128];
  else if (tid < 256) sb[tid]       = b2[tid - 192];
  else if (tid < 384) sb[tid]       = s3[tid - 256];
  else if (tid < 512) sb[tid]       = b3[tid - 384];

  // ---- Phase 0: ball query, one wave per center ----
  if (w < 8) {
    int g = (blockIdx.x << 3) + w;
    int b = g >> 10;
    const float* base = xyz + (size_t)b * NPTS * 3;
    float cx = nx[g * 3 + 0], cy = nx[g * 3 + 1], cz = nx[g * 3 + 2];
    int cnt = 0, fidx = -1;
    for (int c0 = 0; c0 < NPTS && cnt < NSAMPLE; c0 += 64) {
      int i = c0 + lane;
      float dx = __fsub_rn(base[i * 3 + 0], cx);
      float dy = __fsub_rn(base[i * 3 + 1], cy);
      float dz = __fsub_rn(base[i * 3 + 2], cz);
      float d2 = __fadd_rn(__fadd_rn(__fmul_rn(dx, dx), __fmul_rn(dy, dy)),
                           __fmul_rn(dz, dz));
      bool pred = d2 < R2f;
      unsigned long long mk = __ballot(pred);
      if (pred) {
        int rank = cnt + __popcll(mk & ((1ull << lane) - 1ull));
        if (rank < NSAMPLE) lid8[w][rank] = i;
        if (rank == 0) fidx = i;
      }
      cnt += __popcll(mk);
    }
#pragma unroll
    for (int off = 32; off >= 1; off >>= 1) {
      int o = __shfl_xor(fidx, off);
      fidx = o > fidx ? o : fidx;
    }
    if (lane >= cnt && lane < NSAMPLE) lid8[w][lane] = fidx;
  }
  __syncthreads();

  // ---- per-center MLP ----
  for (int ci = 0; ci < 8; ++ci) {
    int g = (blockIdx.x << 3) + ci;
    int b = g >> 10, m = g & 1023;

    // gather xs[c][k]  (+ init hm)
    {
      int k = tid >> 5, c0 = tid & 31;
      int id = lid8[ci][k];
      for (int c = c0; c < CIN; c += 32) {
        float val;
        if (c < 3)
          val = __fsub_rn(xyz[((size_t)b * NPTS + id) * 3 + c], nx[g * 3 + c]);
        else if (featsT)
          val = featsT[((size_t)b * NPTS + id) * 64 + (c - 3)];
        else
          val = feats[((size_t)(b * 64 + (c - 3))) * NPTS + id];
        xs[c * 34 + k] = val;
      }
      if (tid < 128) hm[tid] = 0;
    }
    __syncthreads();

    // L1: 67 -> 64
    {
      int oc = tid & 63, k0 = (tid >> 6) << 1;
      float a0 = 0.f, a1 = 0.f;
#pragma unroll 4
      for (int i = 0; i < CIN; ++i) {
        float ww = W1t[i * 64 + oc];
        a0 = fmaf(ww, xs[i * 34 + k0], a0);
        a1 = fmaf(ww, xs[i * 34 + k0 + 1], a1);
      }
      float s = sb[oc], bb = sb[64 + oc];
      h1[oc * 34 + k0]     = fmaxf(fmaf(a0, s, bb), 0.f);
      h1[oc * 34 + k0 + 1] = fmaxf(fmaf(a1, s, bb), 0.f);
    }
    __syncthreads();

    // L2: 64 -> 64
    {
      int oc = tid & 63, k0 = (tid >> 6) << 1;
      float a0 = 0.f, a1 = 0.f;
#pragma unroll 4
      for (int i = 0; i < 64; ++i) {
        float ww = W2t[i * 64 + oc];
        a0 = fmaf(ww, h1[i * 34 + k0], a0);
        a1 = fmaf(ww, h1[i * 34 + k0 + 1], a1);
      }
      float s = sb[128 + oc], bb = sb[192 + oc];
      h2[oc * 34 + k0]     = fmaxf(fmaf(a0, s, bb), 0.f);
      h2[oc * 34 + k0 + 1] = fmaxf(fmaf(a1, s, bb), 0.f);
    }
    __syncthreads();

    // L3: 64 -> 128, fused max over k
    {
      int oc = tid & 127, k0 = (tid >> 7) << 2;
      const float4* W3v = reinterpret_cast<const float4*>(W3);
      float a0 = 0.f, a1 = 0.f, a2 = 0.f, a3 = 0.f;
#pragma unroll 4
      for (int i4 = 0; i4 < 16; ++i4) {
        float4 wv = W3v[oc * 16 + i4];
        const float* hr = &h2[(i4 * 4) * 34 + k0];
        a0 = fmaf(wv.x, hr[0], a0); a1 = fmaf(wv.x, hr[1], a1);
        a2 = fmaf(wv.x, hr[2], a2); a3 = fmaf(wv.x, hr[3], a3);
        hr += 34;
        a0 = fmaf(wv.y, hr[0], a0); a1 = fmaf(wv.y, hr[1], a1);
        a2 = fmaf(wv.y, hr[2], a2); a3 = fmaf(wv.y, hr[3], a3);
        hr += 34;
        a0 = fmaf(wv.z, hr[0], a0); a1 = fmaf(wv.z, hr[1], a1);
        a2 = fmaf(wv.z, hr[2], a2); a3 = fmaf(wv.z, hr[3], a3);
        hr += 34;
        a0 = fmaf(wv.w, hr[0], a0); a1 = fmaf(wv.w, hr[1], a1);
        a2 = fmaf(wv.w, hr[2], a2); a3 = fmaf(wv.w, hr[3], a3);
      }
      float s = sb[256 + oc], bb = sb[384 + oc];
      float v0 = fmaxf(fmaf(a0, s, bb), 0.f);
      float v1 = fmaxf(fmaf(a1, s, bb), 0.f);
      float v2 = fmaxf(fmaf(a2, s, bb), 0.f);
      float v3 = fmaxf(fmaf(a3, s, bb), 0.f);
      float mv = fmaxf(fmaxf(v0, v1), fmaxf(v2, v3));
      atomicMax(&hm[oc], __float_as_int(mv));   // values >= 0: int order == float order
    }
    __syncthreads();

    if (tid < 128)
      outF[(((size_t)b * 128 + tid) << 10) + m] = __int_as_float(hm[tid]);
    __syncthreads();
  }
}

// ---------------------------------------------------------------------------
extern "C" void kernel_launch(void* const* d_in, const int* in_sizes, int n_in,
                              void* d_out, int out_size, void* d_ws, size_t ws_size,
                              hipStream_t stream)
{
  if (n_in < 11) return;
  const float* xyz   = (const float*)d_in[0];
  const float* feats = (const float*)d_in[1];
  const float* W1 = (const float*)d_in[2];
  const float* s1 = (const float*)d_in[3];
  const float* b1 = (const float*)d_in[4];
  const float* W2 = (const float*)d_in[5];
  const float* s2 = (const float*)d_in[6];
  const float* b2 = (const float*)d_in[7];
  const float* W3 = (const float*)d_in[8];
  const float* s3 = (const float*)d_in[9];
  const float* b3 = (const float*)d_in[10];
  float* out = (float*)d_out;

  // optional workspace: transposed features (B,N,64)
  float* featsT = nullptr;
  size_t needT = (size_t)BATCH * NPTS * 64 * sizeof(float);
  if (ws_size >= needT) featsT = (float*)d_ws;

  fps_kernel<<<BATCH, FPS_T, 0, stream>>>(xyz, out);
  if (featsT) transpose_kernel<<<BATCH * 256, 256, 0, stream>>>(feats, featsT);
  mlp_kernel<<<512, 1024, 0, stream>>>(xyz, feats, featsT, out,
                                       W1, s1, b1, W2, s2, b2, W3, s3, b3,
                                       out + BATCH * NPOINT * 3);
}